// Round 3
// baseline (34507.535 us; speedup 1.0000x reference)
//
#include <hip/hip_runtime.h>
#include <hip/hip_bf16.h>
#include <math.h>

// Problem constants
#define BB 256     // batch
#define TT 128     // timesteps
#define HH 256     // hidden
#define G4H 1024   // 4*H
#define DINM 512   // mamba d_in = 2H
#define NB 4       // batch rows per workgroup

using bf = __hip_bfloat16;

// ---- workspace layout ----
// bf16 region (element offsets):
constexpr size_t U_WIHT0 = 0;                               // (2,128,1024)
constexpr size_t U_WHHT0 = U_WIHT0 + (size_t)2*128*1024;    // (2,256,1024)
constexpr size_t U_WIHT1 = U_WHHT0 + (size_t)2*256*1024;    // (2,512,1024)
constexpr size_t U_WHHT1 = U_WIHT1 + (size_t)2*512*1024;    // (2,256,1024)
constexpr size_t U_INPT  = U_WHHT1 + (size_t)2*256*1024;    // (256,1024)
constexpr size_t U_OUTPT = U_INPT  + (size_t)256*1024;      // (512,256)
constexpr size_t U_L0OUT = U_OUTPT + (size_t)512*256;       // (B,T,512) bf16
constexpr size_t U_END   = U_L0OUT + (size_t)BB*TT*512;
constexpr size_t FBYTE_OFF = U_END * 2;                     // byte offset of fp32 region
// fp32 region (element offsets from (float*)((char*)ws + FBYTE_OFF)):
constexpr size_t F_BSUM0 = 0;                // (2,1024)
constexpr size_t F_BSUM1 = F_BSUM0 + 2048;   // (2,1024)
constexpr size_t F_XPT   = F_BSUM1 + 2048;   // (512,48)
constexpr size_t F_DTPT  = F_XPT + 512*48;   // (16,512)
constexpr size_t F_CW1   = F_DTPT + 16*512;  // (512)
constexpr size_t F_CB    = F_CW1 + 512;      // (512)
constexpr size_t F_DTB   = F_CB + 512;       // (512)
constexpr size_t F_DM    = F_DTB + 512;      // (512)
constexpr size_t F_H0    = F_DM + 512;       // (2,B,256)
constexpr size_t F_C0    = F_H0 + 2*BB*256;
constexpr size_t F_H1    = F_C0 + 2*BB*256;
constexpr size_t F_C1    = F_H1 + 2*BB*256;
// total ~41.3 MB

__device__ __forceinline__ float b2f(bf v) { return __bfloat162float(v); }
__device__ __forceinline__ bf f2b(float v) { return __float2bfloat16(v); }
__device__ __forceinline__ float sigmoidf_(float x) { return 1.0f / (1.0f + __expf(-x)); }
__device__ __forceinline__ float softplusf_(float x) {
    return log1pf(__expf(-fabsf(x))) + fmaxf(x, 0.0f);   // stable, matches jax.nn.softplus
}

__device__ __forceinline__ float loadval(const float* p) { return *p; }
__device__ __forceinline__ float loadval(const bf* p) { return __bfloat162float(*p); }
__device__ __forceinline__ void storeval(float* p, float v) { *p = v; }
__device__ __forceinline__ void storeval(bf* p, float v) { *p = __float2bfloat16(v); }

// ---------------- prep: transpose weights fp32->bf16, pre-sum biases, zero states ----------------
__global__ __launch_bounds__(256)
void prep_kernel(
    const float* __restrict__ w_ih_l0, const float* __restrict__ w_hh_l0,
    const float* __restrict__ b_ih_l0, const float* __restrict__ b_hh_l0,
    const float* __restrict__ w_ih_l1, const float* __restrict__ w_hh_l1,
    const float* __restrict__ b_ih_l1, const float* __restrict__ b_hh_l1,
    const float* __restrict__ in_proj_w, const float* __restrict__ conv_w,
    const float* __restrict__ conv_b, const float* __restrict__ x_proj_w,
    const float* __restrict__ dt_proj_w, const float* __restrict__ dt_proj_b,
    const float* __restrict__ D_m, const float* __restrict__ out_proj_w,
    bf* __restrict__ wsu, float* __restrict__ wsf)
{
    const int nt = gridDim.x * blockDim.x;
    const int g0 = blockIdx.x * blockDim.x + threadIdx.x;

    // w_ihT_l0 (2,128,1024) <- w_ih_l0 (2,1024,128)
    for (int idx = g0; idx < 2*128*1024; idx += nt) {
        int d = idx >> 17, rem = idx & 131071;
        int i = rem >> 10, j = rem & 1023;
        wsu[U_WIHT0 + idx] = f2b(w_ih_l0[(size_t)d*131072 + (size_t)j*128 + i]);
    }
    // w_hhT_l0 (2,256,1024) <- (2,1024,256)
    for (int idx = g0; idx < 2*256*1024; idx += nt) {
        int d = idx >> 18, rem = idx & 262143;
        int k = rem >> 10, j = rem & 1023;
        wsu[U_WHHT0 + idx] = f2b(w_hh_l0[(size_t)d*262144 + (size_t)j*256 + k]);
    }
    // w_ihT_l1 (2,512,1024) <- (2,1024,512)
    for (int idx = g0; idx < 2*512*1024; idx += nt) {
        int d = idx >> 19, rem = idx & 524287;
        int i = rem >> 10, j = rem & 1023;
        wsu[U_WIHT1 + idx] = f2b(w_ih_l1[(size_t)d*524288 + (size_t)j*512 + i]);
    }
    // w_hhT_l1 (2,256,1024) <- (2,1024,256)
    for (int idx = g0; idx < 2*256*1024; idx += nt) {
        int d = idx >> 18, rem = idx & 262143;
        int k = rem >> 10, j = rem & 1023;
        wsu[U_WHHT1 + idx] = f2b(w_hh_l1[(size_t)d*262144 + (size_t)j*256 + k]);
    }
    // in_projT (256,1024) <- (1024,256)
    for (int idx = g0; idx < 256*1024; idx += nt) {
        int k = idx >> 10, j = idx & 1023;
        wsu[U_INPT + idx] = f2b(in_proj_w[(size_t)j*256 + k]);
    }
    // out_projT (512,256) <- (256,512)
    for (int idx = g0; idx < 512*256; idx += nt) {
        int d = idx >> 8, k = idx & 255;
        wsu[U_OUTPT + idx] = f2b(out_proj_w[(size_t)k*512 + d]);
    }
    // bias sums (2,1024) each layer
    for (int idx = g0; idx < 2048; idx += nt) {
        wsf[F_BSUM0 + idx] = b_ih_l0[idx] + b_hh_l0[idx];
        wsf[F_BSUM1 + idx] = b_ih_l1[idx] + b_hh_l1[idx];
    }
    // x_projT (512,48) <- (48,512)
    for (int idx = g0; idx < 512*48; idx += nt) {
        int d = idx / 48, p = idx % 48;
        wsf[F_XPT + idx] = x_proj_w[(size_t)p*512 + d];
    }
    // dt_projT (16,512) <- (512,16)
    for (int idx = g0; idx < 16*512; idx += nt) {
        int p = idx >> 9, d = idx & 511;
        wsf[F_DTPT + idx] = dt_proj_w[(size_t)d*16 + p];
    }
    // small vectors
    for (int idx = g0; idx < 512; idx += nt) {
        wsf[F_CW1 + idx] = conv_w[idx*2 + 1];  // conv_w[:, -1]
        wsf[F_CB  + idx] = conv_b[idx];
        wsf[F_DTB + idx] = dt_proj_b[idx];
        wsf[F_DM  + idx] = D_m[idx];
    }
    // zero initial states for layer 0
    for (int idx = g0; idx < 2*BB*256; idx += nt) {
        wsf[F_H0 + idx] = 0.0f;
        wsf[F_C0 + idx] = 0.0f;
    }
}

// ---------------- layer kernel: one WG owns NB batch rows of one direction, loops all T ----------------
template<int DIN, typename TIn, typename TOut>
__global__ __launch_bounds__(256)
void layer_kernel(const TIn* __restrict__ in,          // (B,T,DIN)
                  TOut* __restrict__ out,               // (B,T,512), this dir writes channels [dir*256, +256)
                  const bf* __restrict__ wsu,
                  const float* __restrict__ wsf,
                  const bf* __restrict__ wihT_all,      // (2,DIN,1024) bf16
                  const bf* __restrict__ whhT_all,      // (2,256,1024) bf16
                  const float* __restrict__ bsum_all,   // (2,1024)
                  const float* __restrict__ h_init, const float* __restrict__ c_init,  // (2,B,256)
                  float* __restrict__ h_fin, float* __restrict__ c_fin)                // (2,B,256)
{
    const int tid = threadIdx.x;
    const int dir = blockIdx.y;
    const int b0 = blockIdx.x * NB;

    const bf*  wih   = wihT_all + (size_t)dir * DIN * G4H;
    const bf*  whh   = whhT_all + (size_t)dir * HH * G4H;
    const float* bs  = bsum_all + (size_t)dir * G4H;
    const bf*  inpT  = wsu + U_INPT;
    const bf*  outpT = wsu + U_OUTPT;
    const float* xpT  = wsf + F_XPT;
    const float* dtpT = wsf + F_DTPT;
    const float* cw1  = wsf + F_CW1;
    const float* cb   = wsf + F_CB;
    const float* dtb  = wsf + F_DTB;
    const float* Dm   = wsf + F_DM;

    __shared__ float sh_h[NB][HH];
    __shared__ float sh_c[NB][HH];
    __shared__ float sh_u[NB][DIN];
    __shared__ float sh_g[NB][G4H];
    __shared__ float sh_xz[NB][G4H];
    __shared__ float sh_xdbl[NB][48];
    __shared__ float sh_y[NB][DINM];
    __shared__ float sh_mo[NB][HH];

    // init h, c
    for (int idx = tid; idx < NB*HH; idx += 256) {
        int r = idx >> 8, k = idx & 255;
        sh_h[r][k] = h_init[((size_t)dir*BB + b0 + r)*HH + k];
        sh_c[r][k] = c_init[((size_t)dir*BB + b0 + r)*HH + k];
    }
    __syncthreads();

    for (int t = 0; t < TT; ++t) {
        const int t_in = dir ? (TT - 1 - t) : t;

        // load layer input u for this timestep
        for (int idx = tid; idx < NB*DIN; idx += 256) {
            int r = idx / DIN, d = idx % DIN;
            sh_u[r][d] = loadval(&in[((size_t)(b0 + r)*TT + t_in)*DIN + d]);
        }
        __syncthreads();

        // ---- g = u @ w_ih^T + h @ w_hh^T  (1024 outputs x NB rows) ----
        {
            float a0[NB], a1[NB], a2[NB], a3[NB];
            #pragma unroll
            for (int r = 0; r < NB; ++r) { a0[r]=0.f; a1[r]=0.f; a2[r]=0.f; a3[r]=0.f; }
            #pragma unroll 2
            for (int k = 0; k < DIN; ++k) {
                float w0 = b2f(wih[(size_t)k*G4H + tid]);
                float w1 = b2f(wih[(size_t)k*G4H + tid + 256]);
                float w2 = b2f(wih[(size_t)k*G4H + tid + 512]);
                float w3 = b2f(wih[(size_t)k*G4H + tid + 768]);
                #pragma unroll
                for (int r = 0; r < NB; ++r) {
                    float u = sh_u[r][k];
                    a0[r] = fmaf(w0, u, a0[r]);
                    a1[r] = fmaf(w1, u, a1[r]);
                    a2[r] = fmaf(w2, u, a2[r]);
                    a3[r] = fmaf(w3, u, a3[r]);
                }
            }
            #pragma unroll 2
            for (int k = 0; k < HH; ++k) {
                float w0 = b2f(whh[(size_t)k*G4H + tid]);
                float w1 = b2f(whh[(size_t)k*G4H + tid + 256]);
                float w2 = b2f(whh[(size_t)k*G4H + tid + 512]);
                float w3 = b2f(whh[(size_t)k*G4H + tid + 768]);
                #pragma unroll
                for (int r = 0; r < NB; ++r) {
                    float hv = sh_h[r][k];
                    a0[r] = fmaf(w0, hv, a0[r]);
                    a1[r] = fmaf(w1, hv, a1[r]);
                    a2[r] = fmaf(w2, hv, a2[r]);
                    a3[r] = fmaf(w3, hv, a3[r]);
                }
            }
            #pragma unroll
            for (int r = 0; r < NB; ++r) {
                sh_g[r][tid]       = a0[r];
                sh_g[r][tid + 256] = a1[r];
                sh_g[r][tid + 512] = a2[r];
                sh_g[r][tid + 768] = a3[r];
            }
        }
        __syncthreads();

        // ---- mamba: xz = u_m @ in_proj^T, u_m = g[:, :256] (no bias) ----
        {
            float a0[NB], a1[NB], a2[NB], a3[NB];
            #pragma unroll
            for (int r = 0; r < NB; ++r) { a0[r]=0.f; a1[r]=0.f; a2[r]=0.f; a3[r]=0.f; }
            #pragma unroll 2
            for (int k = 0; k < HH; ++k) {
                float w0 = b2f(inpT[(size_t)k*G4H + tid]);
                float w1 = b2f(inpT[(size_t)k*G4H + tid + 256]);
                float w2 = b2f(inpT[(size_t)k*G4H + tid + 512]);
                float w3 = b2f(inpT[(size_t)k*G4H + tid + 768]);
                #pragma unroll
                for (int r = 0; r < NB; ++r) {
                    float u = sh_g[r][k];
                    a0[r] = fmaf(w0, u, a0[r]);
                    a1[r] = fmaf(w1, u, a1[r]);
                    a2[r] = fmaf(w2, u, a2[r]);
                    a3[r] = fmaf(w3, u, a3[r]);
                }
            }
            #pragma unroll
            for (int r = 0; r < NB; ++r) {
                sh_xz[r][tid]       = a0[r];
                sh_xz[r][tid + 256] = a1[r];
                sh_xz[r][tid + 512] = a2[r];
                sh_xz[r][tid + 768] = a3[r];
            }
        }
        __syncthreads();

        // ---- xm = silu(xz[:512]*cw1 + cb), in place (z stays at [512:1024]) ----
        for (int idx = tid; idx < NB*DINM; idx += 256) {
            int r = idx >> 9, d = idx & 511;
            float v = fmaf(sh_xz[r][d], cw1[d], cb[d]);
            sh_xz[r][d] = v * sigmoidf_(v);
        }
        __syncthreads();

        // ---- x_dbl = xm @ x_proj^T (48 outputs x NB rows) ----
        if (tid < NB*48) {
            int r = tid / 48, p = tid % 48;
            float acc = 0.f;
            for (int d = 0; d < DINM; ++d)
                acc = fmaf(sh_xz[r][d], xpT[(size_t)d*48 + p], acc);
            sh_xdbl[r][p] = acc;
        }
        __syncthreads();

        // ---- delta/bc/y fused (512 outputs x NB rows) ----
        for (int idx = tid; idx < NB*DINM; idx += 256) {
            int r = idx >> 9, d = idx & 511;
            float acc = dtb[d];
            #pragma unroll
            for (int p = 0; p < 16; ++p)
                acc = fmaf(sh_xdbl[r][p], dtpT[p*DINM + d], acc);
            float delta = softplusf_(acc);
            float bc = 0.f;
            #pragma unroll
            for (int s = 0; s < 16; ++s)
                bc = fmaf(sh_xdbl[r][16 + s], sh_xdbl[r][32 + s], bc);
            float xm = sh_xz[r][d];
            float z  = sh_xz[r][512 + d];
            float yv = (delta * bc + Dm[d]) * xm;
            yv *= z * sigmoidf_(z);
            sh_y[r][d] = yv;
        }
        __syncthreads();

        // ---- mamba out = y @ out_proj^T (256 outputs x NB rows) ----
        {
            float acc[NB];
            #pragma unroll
            for (int r = 0; r < NB; ++r) acc[r] = 0.f;
            #pragma unroll 2
            for (int d = 0; d < DINM; ++d) {
                float w = b2f(outpT[(size_t)d*HH + tid]);
                #pragma unroll
                for (int r = 0; r < NB; ++r)
                    acc[r] = fmaf(sh_y[r][d], w, acc[r]);
            }
            #pragma unroll
            for (int r = 0; r < NB; ++r) sh_mo[r][tid] = acc[r];
        }
        __syncthreads();

        // ---- gates + state update + store h ----
        for (int idx = tid; idx < NB*HH; idx += 256) {
            int r = idx >> 8, k = idx & 255;
            float i_t = sigmoidf_(sh_mo[r][k] + bs[k]);
            float f_t = sigmoidf_(sh_g[r][256 + k] + bs[256 + k]);
            float g_t = tanhf(sh_g[r][512 + k] + bs[512 + k]);
            float o_t = sigmoidf_(sh_g[r][768 + k] + bs[768 + k]);
            float cv = f_t * sh_c[r][k] + i_t * g_t;
            float hv = o_t * tanhf(cv);
            sh_c[r][k] = cv;
            sh_h[r][k] = hv;
            storeval(&out[((size_t)(b0 + r)*TT + t_in)*512 + (size_t)dir*HH + k], hv);
        }
        __syncthreads();
    }

    // write final states (become next layer's initial states)
    for (int idx = tid; idx < NB*HH; idx += 256) {
        int r = idx >> 8, k = idx & 255;
        h_fin[((size_t)dir*BB + b0 + r)*HH + k] = sh_h[r][k];
        c_fin[((size_t)dir*BB + b0 + r)*HH + k] = sh_c[r][k];
    }
}

extern "C" void kernel_launch(void* const* d_in, const int* in_sizes, int n_in,
                              void* d_out, int out_size, void* d_ws, size_t ws_size,
                              hipStream_t stream)
{
    // Reference dtypes are float32 throughout -> all inputs are fp32, output fp32.
    const float* x          = (const float*)d_in[0];
    const float* w_ih_l0    = (const float*)d_in[1];
    const float* w_hh_l0    = (const float*)d_in[2];
    const float* b_ih_l0    = (const float*)d_in[3];
    const float* b_hh_l0    = (const float*)d_in[4];
    const float* w_ih_l1    = (const float*)d_in[5];
    const float* w_hh_l1    = (const float*)d_in[6];
    const float* b_ih_l1    = (const float*)d_in[7];
    const float* b_hh_l1    = (const float*)d_in[8];
    const float* in_proj_w  = (const float*)d_in[9];
    const float* conv_w     = (const float*)d_in[10];
    const float* conv_b     = (const float*)d_in[11];
    const float* x_proj_w   = (const float*)d_in[12];
    const float* dt_proj_w  = (const float*)d_in[13];
    const float* dt_proj_b  = (const float*)d_in[14];
    const float* D_m        = (const float*)d_in[15];
    const float* out_proj_w = (const float*)d_in[16];

    bf*    wsu = (bf*)d_ws;
    float* wsf = (float*)((char*)d_ws + FBYTE_OFF);

    prep_kernel<<<256, 256, 0, stream>>>(
        w_ih_l0, w_hh_l0, b_ih_l0, b_hh_l0,
        w_ih_l1, w_hh_l1, b_ih_l1, b_hh_l1,
        in_proj_w, conv_w, conv_b, x_proj_w,
        dt_proj_w, dt_proj_b, D_m, out_proj_w, wsu, wsf);

    dim3 grid(BB / NB, 2);

    bf* l0out = wsu + U_L0OUT;

    // layer 0: input x (fp32, DIN=128) -> l0out (bf16), zero init states, finals -> H1/C1
    layer_kernel<128, float, bf><<<grid, 256, 0, stream>>>(
        x, l0out, wsu, wsf,
        wsu + U_WIHT0, wsu + U_WHHT0, wsf + F_BSUM0,
        wsf + F_H0, wsf + F_C0, wsf + F_H1, wsf + F_C1);

    // layer 1: input l0out (bf16, DIN=512) -> d_out (fp32), init from H1/C1
    layer_kernel<512, bf, float><<<grid, 256, 0, stream>>>(
        l0out, (float*)d_out, wsu, wsf,
        wsu + U_WIHT1, wsu + U_WHHT1, wsf + F_BSUM1,
        wsf + F_H1, wsf + F_C1, wsf + F_H0, wsf + F_C0);
}

// Round 4
// 18699.231 us; speedup vs baseline: 1.8454x; 1.8454x over previous
//
#include <hip/hip_runtime.h>
#include <hip/hip_bf16.h>
#include <math.h>

#define BB 256     // batch
#define TT 128     // timesteps
#define HH 256     // hidden
#define NBR 16     // batch rows per workgroup
#define BLK 512    // threads per block (8 waves)

typedef short bf8 __attribute__((ext_vector_type(8)));   // 8 bf16 (4 VGPRs)
typedef float f4  __attribute__((ext_vector_type(4)));   // MFMA accumulator
#define MFMA16 __builtin_amdgcn_mfma_f32_16x16x32_bf16

// ---- workspace layout ----
// bf16(short) region, element offsets:
constexpr size_t U_WC0  = 0;                                  // (2,1024,384) gate cat l0
constexpr size_t U_WC1  = U_WC0 + (size_t)2*1024*384;         // (2,1024,768) gate cat l1
constexpr size_t U_INP  = U_WC1 + (size_t)2*1024*768;         // (1024,256)
constexpr size_t U_XP   = U_INP + (size_t)1024*256;           // (48,512)
constexpr size_t U_OUTP = U_XP  + (size_t)48*512;             // (256,512)
constexpr size_t U_L0   = U_OUTP + (size_t)256*512;           // (B,T,512) l0 output bf16
constexpr size_t U_END  = U_L0 + (size_t)BB*TT*512;
constexpr size_t FOFF   = U_END * 2;                          // byte offset of f32 region
// f32 region:
constexpr size_t F_BSUM0 = 0;                 // (2,1024)
constexpr size_t F_BSUM1 = F_BSUM0 + 2048;    // (2,1024)
constexpr size_t F_H0    = F_BSUM1 + 2048;    // (2,B,256)
constexpr size_t F_C0    = F_H0 + 2*BB*256;
constexpr size_t F_H1    = F_C0 + 2*BB*256;
constexpr size_t F_C1    = F_H1 + 2*BB*256;
// total ~41.2 MB

__device__ __forceinline__ short f2bs(float v) {
    __hip_bfloat16 b = __float2bfloat16(v);
    short s; __builtin_memcpy(&s, &b, 2); return s;
}
__device__ __forceinline__ float bs2f(short s) {
    unsigned int u = ((unsigned int)(unsigned short)s) << 16;
    float f; __builtin_memcpy(&f, &u, 4); return f;
}
__device__ __forceinline__ float sigmoidf_(float x) { return 1.0f / (1.0f + __expf(-x)); }
__device__ __forceinline__ float softplusf_(float x) {
    return log1pf(__expf(-fabsf(x))) + fmaxf(x, 0.0f);
}
__device__ __forceinline__ float loadval(const float* p) { return *p; }
__device__ __forceinline__ float loadval(const short* p) { return bs2f(*p); }
__device__ __forceinline__ void storeval(float* p, float v) { *p = v; }
__device__ __forceinline__ void storeval(short* p, float v) { *p = f2bs(v); }

// ---------------- prep: convert weights f32->bf16 (original [n][k] layout), cat gates, bsum, zero states ----
__global__ __launch_bounds__(256)
void prep2(const float* __restrict__ w_ih_l0, const float* __restrict__ w_hh_l0,
           const float* __restrict__ b_ih_l0, const float* __restrict__ b_hh_l0,
           const float* __restrict__ w_ih_l1, const float* __restrict__ w_hh_l1,
           const float* __restrict__ b_ih_l1, const float* __restrict__ b_hh_l1,
           const float* __restrict__ in_proj_w, const float* __restrict__ x_proj_w,
           const float* __restrict__ out_proj_w,
           short* __restrict__ wsu, float* __restrict__ wsf)
{
    const int nt = gridDim.x * blockDim.x;
    const int g0 = blockIdx.x * blockDim.x + threadIdx.x;

    // Wcat0 (2,1024,384): k<128 from w_ih_l0 (2,1024,128), else w_hh_l0 (2,1024,256)
    for (int idx = g0; idx < 2*1024*384; idx += nt) {
        int dir = idx / (1024*384), rem = idx % (1024*384);
        int n = rem / 384, k = rem % 384;
        float v = (k < 128) ? w_ih_l0[(size_t)dir*1024*128 + (size_t)n*128 + k]
                            : w_hh_l0[(size_t)dir*1024*256 + (size_t)n*256 + (k-128)];
        wsu[U_WC0 + idx] = f2bs(v);
    }
    // Wcat1 (2,1024,768): k<512 from w_ih_l1 (2,1024,512), else w_hh_l1
    for (int idx = g0; idx < 2*1024*768; idx += nt) {
        int dir = idx / (1024*768), rem = idx % (1024*768);
        int n = rem / 768, k = rem % 768;
        float v = (k < 512) ? w_ih_l1[(size_t)dir*1024*512 + (size_t)n*512 + k]
                            : w_hh_l1[(size_t)dir*1024*256 + (size_t)n*256 + (k-512)];
        wsu[U_WC1 + idx] = f2bs(v);
    }
    for (int idx = g0; idx < 1024*256; idx += nt) wsu[U_INP  + idx] = f2bs(in_proj_w[idx]);
    for (int idx = g0; idx < 48*512;   idx += nt) wsu[U_XP   + idx] = f2bs(x_proj_w[idx]);
    for (int idx = g0; idx < 256*512;  idx += nt) wsu[U_OUTP + idx] = f2bs(out_proj_w[idx]);
    for (int idx = g0; idx < 2048; idx += nt) {
        wsf[F_BSUM0 + idx] = b_ih_l0[idx] + b_hh_l0[idx];
        wsf[F_BSUM1 + idx] = b_ih_l1[idx] + b_hh_l1[idx];
    }
    for (int idx = g0; idx < 2*BB*256; idx += nt) {
        wsf[F_H0 + idx] = 0.0f;
        wsf[F_C0 + idx] = 0.0f;
    }
}

// ---------------- MFMA layer kernel: one WG = 16 batch rows of one direction, loops all T ----------------
// mfma_f32_16x16x32_bf16 layouts (HW-verified m89/m91):
//   A: row m = lane&15, k = (lane>>4)*8 + j  (8 contiguous k)
//   B: col n = lane&15, k = (lane>>4)*8 + j  -> W stored [n][k]: 16B contiguous load
//   C: col n = lane&15, row m = (lane>>4)*4 + reg
template<int DIN, typename TIn, typename TOut>
__global__ __launch_bounds__(BLK, 2)
void layer_mfma(const TIn* __restrict__ in,        // (B,T,DIN)
                TOut* __restrict__ out,             // (B,T,512): this dir writes [dir*256, +256)
                const short* __restrict__ Wcat,     // (2,1024,KG) bf16 [dir][n][k]
                const short* __restrict__ Winp,     // (1024,256)
                const short* __restrict__ Wxp,      // (48,512)
                const short* __restrict__ Woutp,    // (256,512)
                const float* __restrict__ bsum_all, // (2,1024)
                const float* __restrict__ conv_w,   // (512,2) f32
                const float* __restrict__ conv_b,   // (512)
                const float* __restrict__ dtw,      // (512,16) f32
                const float* __restrict__ dtb,      // (512)
                const float* __restrict__ Dm,       // (512)
                const float* __restrict__ h_init, const float* __restrict__ c_init,  // (2,B,256)
                float* __restrict__ h_fin, float* __restrict__ c_fin)
{
    constexpr int KG = DIN + 256;          // gate GEMM K (u|h concatenated)
    const int tid = threadIdx.x;
    const int wv = tid >> 6, ln = tid & 63;
    const int lr = ln & 15, lq = ln >> 4;  // lane row/col-in-tile, k-quad
    const int dir = blockIdx.y;
    const int b0 = blockIdx.x * NBR;

    const short* Wg = Wcat + (size_t)dir * 1024 * KG;

    // A-operand row strides: in shorts; ≡4 banks mod 32 -> conflict-free b128 reads
    __shared__ __attribute__((aligned(16))) short sA[16*776];    // [u(0..DIN) | h(DIN..DIN+256)]
    __shared__ __attribute__((aligned(16))) short sUm[16*264];   // mamba input (g[:, :256]) bf16
    __shared__ __attribute__((aligned(16))) short sXm[16*520];   // xm, later y (in-place)
    __shared__ __attribute__((aligned(16))) short sZs[16*520];   // silu(z)
    __shared__ float sF[16*264], sG[16*264], sO[16*264];         // activated gates f32
    __shared__ float sXd[16*52];                                 // x_dbl f32
    __shared__ float sC[16*256];                                 // cell state f32
    __shared__ float sBsum[1024];

    for (int idx = tid; idx < 1024; idx += BLK) sBsum[idx] = bsum_all[dir*1024 + idx];
    for (int idx = tid; idx < 16*256; idx += BLK) {
        int r = idx >> 8, k = idx & 255;
        size_t src = ((size_t)dir*BB + b0 + r)*256 + k;
        sA[r*776 + DIN + k] = f2bs(h_init[src]);
        sC[idx] = c_init[src];
    }
    __syncthreads();

    for (int t = 0; t < TT; ++t) {
        const int t_in = dir ? (TT - 1 - t) : t;

        // ---- load u into A_cat[.,0..DIN) ----
        for (int idx = tid; idx < 16*DIN; idx += BLK) {
            int r = idx / DIN, d = idx % DIN;
            sA[r*776 + d] = f2bs(loadval(&in[((size_t)(b0 + r)*TT + t_in)*DIN + d]));
        }
        __syncthreads();

        // ---- GEMM1: gates[16x1024] = [u|h] @ Wcat^T, K=KG ----
        {
            f4 acc[8];
            #pragma unroll
            for (int i = 0; i < 8; ++i) acc[i] = (f4){0.f,0.f,0.f,0.f};
            const int arow = lr*776 + lq*8;
            #pragma unroll 2
            for (int k0 = 0; k0 < KG; k0 += 32) {
                bf8 a = *(const bf8*)&sA[arow + k0];
                #pragma unroll
                for (int i = 0; i < 8; ++i) {
                    int n = wv*128 + i*16 + lr;
                    bf8 b = *(const bf8*)&Wg[(size_t)n*KG + k0 + lq*8];
                    acc[i] = MFMA16(a, b, acc[i], 0, 0, 0);
                }
            }
            if (wv < 2) {
                // cols 0..255: raw mamba input (no bias)
                #pragma unroll
                for (int i = 0; i < 8; ++i) {
                    int col = wv*128 + i*16 + lr;
                    #pragma unroll
                    for (int j = 0; j < 4; ++j)
                        sUm[(lq*4+j)*264 + col] = f2bs(acc[i][j]);
                }
            } else {
                // cols 256..1023: + bsum, activate, store f32
                float* dst = (wv < 4) ? sF : (wv < 6) ? sG : sO;
                const bool istanh = (wv >= 4 && wv < 6);
                #pragma unroll
                for (int i = 0; i < 8; ++i) {
                    int col = wv*128 + i*16 + lr;
                    int kk = col & 255;
                    float bsv = sBsum[col];
                    #pragma unroll
                    for (int j = 0; j < 4; ++j) {
                        float v = acc[i][j] + bsv;
                        dst[(lq*4+j)*264 + kk] = istanh ? tanhf(v) : sigmoidf_(v);
                    }
                }
            }
        }
        __syncthreads();

        // ---- GEMM2: xz[16x1024] = um @ Winp^T, K=256; fuse conv+silu ----
        {
            f4 acc[8];
            #pragma unroll
            for (int i = 0; i < 8; ++i) acc[i] = (f4){0.f,0.f,0.f,0.f};
            const int arow = lr*264 + lq*8;
            #pragma unroll 2
            for (int k0 = 0; k0 < 256; k0 += 32) {
                bf8 a = *(const bf8*)&sUm[arow + k0];
                #pragma unroll
                for (int i = 0; i < 8; ++i) {
                    int n = wv*128 + i*16 + lr;
                    bf8 b = *(const bf8*)&Winp[(size_t)n*256 + k0 + lq*8];
                    acc[i] = MFMA16(a, b, acc[i], 0, 0, 0);
                }
            }
            #pragma unroll
            for (int i = 0; i < 8; ++i) {
                int col = wv*128 + i*16 + lr;
                if (col < 512) {
                    float cw = conv_w[col*2 + 1], cbv = conv_b[col];
                    #pragma unroll
                    for (int j = 0; j < 4; ++j) {
                        float v = fmaf(acc[i][j], cw, cbv);
                        sXm[(lq*4+j)*520 + col] = f2bs(v * sigmoidf_(v));
                    }
                } else {
                    int cz = col - 512;
                    #pragma unroll
                    for (int j = 0; j < 4; ++j) {
                        float z = acc[i][j];
                        sZs[(lq*4+j)*520 + cz] = f2bs(z * sigmoidf_(z));
                    }
                }
            }
        }
        __syncthreads();

        // ---- GEMM3: x_dbl[16x48] = xm @ Wxp^T, K=512 (waves 0..2) ----
        if (wv < 3) {
            f4 acc = (f4){0.f,0.f,0.f,0.f};
            const int arow = lr*520 + lq*8;
            #pragma unroll 2
            for (int k0 = 0; k0 < 512; k0 += 32) {
                bf8 a = *(const bf8*)&sXm[arow + k0];
                bf8 b = *(const bf8*)&Wxp[(size_t)(wv*16 + lr)*512 + k0 + lq*8];
                acc = MFMA16(a, b, acc, 0, 0, 0);
            }
            #pragma unroll
            for (int j = 0; j < 4; ++j)
                sXd[(lq*4+j)*52 + wv*16 + lr] = acc[j];
        }
        __syncthreads();

        // ---- phase4: delta/bc/y elementwise; y overwrites xm in-place ----
        {
            const int d = tid;   // 512 threads <-> 512 channels
            float w16[16];
            #pragma unroll
            for (int p = 0; p < 16; ++p) w16[p] = dtw[d*16 + p];
            const float dtbv = dtb[d], Dmv = Dm[d];
            for (int r = 0; r < 16; ++r) {
                float dp = dtbv;
                #pragma unroll
                for (int p = 0; p < 16; ++p) dp = fmaf(sXd[r*52 + p], w16[p], dp);
                float bc = 0.f;
                #pragma unroll
                for (int s = 0; s < 16; ++s) bc = fmaf(sXd[r*52 + 16 + s], sXd[r*52 + 32 + s], bc);
                float xmv = bs2f(sXm[r*520 + d]);
                float zsv = bs2f(sZs[r*520 + d]);
                float yv = fmaf(softplusf_(dp), bc, Dmv) * xmv * zsv;
                sXm[r*520 + d] = f2bs(yv);
            }
        }
        __syncthreads();

        // ---- GEMM4: mo[16x256] = y @ Woutp^T, K=512; fuse gate combine ----
        {
            f4 acc[2];
            acc[0] = (f4){0.f,0.f,0.f,0.f};
            acc[1] = (f4){0.f,0.f,0.f,0.f};
            const int arow = lr*520 + lq*8;
            #pragma unroll 2
            for (int k0 = 0; k0 < 512; k0 += 32) {
                bf8 a = *(const bf8*)&sXm[arow + k0];
                #pragma unroll
                for (int i = 0; i < 2; ++i) {
                    int n = wv*32 + i*16 + lr;
                    bf8 b = *(const bf8*)&Woutp[(size_t)n*512 + k0 + lq*8];
                    acc[i] = MFMA16(a, b, acc[i], 0, 0, 0);
                }
            }
            #pragma unroll
            for (int i = 0; i < 2; ++i) {
                int k = wv*32 + i*16 + lr;
                float bsv = sBsum[k];
                #pragma unroll
                for (int j = 0; j < 4; ++j) {
                    int r = lq*4 + j;
                    float i_t = sigmoidf_(acc[i][j] + bsv);
                    float f_t = sF[r*264 + k];
                    float g_t = sG[r*264 + k];
                    float o_t = sO[r*264 + k];
                    float cv = fmaf(f_t, sC[r*256 + k], i_t * g_t);
                    sC[r*256 + k] = cv;
                    float hv = o_t * tanhf(cv);
                    sA[r*776 + DIN + k] = f2bs(hv);
                    storeval(&out[((size_t)(b0 + r)*TT + t_in)*512 + (size_t)dir*256 + k], hv);
                }
            }
        }
        // no sync needed: next u-load writes a disjoint LDS region; its syncthreads
        // orders all combine writes before GEMM1 reads.
    }

    __syncthreads();
    for (int idx = tid; idx < 16*256; idx += BLK) {
        int r = idx >> 8, k = idx & 255;
        size_t dst = ((size_t)dir*BB + b0 + r)*256 + k;
        h_fin[dst] = bs2f(sA[r*776 + DIN + k]);
        c_fin[dst] = sC[idx];
    }
}

extern "C" void kernel_launch(void* const* d_in, const int* in_sizes, int n_in,
                              void* d_out, int out_size, void* d_ws, size_t ws_size,
                              hipStream_t stream)
{
    const float* x          = (const float*)d_in[0];
    const float* w_ih_l0    = (const float*)d_in[1];
    const float* w_hh_l0    = (const float*)d_in[2];
    const float* b_ih_l0    = (const float*)d_in[3];
    const float* b_hh_l0    = (const float*)d_in[4];
    const float* w_ih_l1    = (const float*)d_in[5];
    const float* w_hh_l1    = (const float*)d_in[6];
    const float* b_ih_l1    = (const float*)d_in[7];
    const float* b_hh_l1    = (const float*)d_in[8];
    const float* in_proj_w  = (const float*)d_in[9];
    const float* conv_w     = (const float*)d_in[10];
    const float* conv_b     = (const float*)d_in[11];
    const float* x_proj_w   = (const float*)d_in[12];
    const float* dt_proj_w  = (const float*)d_in[13];
    const float* dt_proj_b  = (const float*)d_in[14];
    const float* D_m        = (const float*)d_in[15];
    const float* out_proj_w = (const float*)d_in[16];

    short* wsu = (short*)d_ws;
    float* wsf = (float*)((char*)d_ws + FOFF);

    prep2<<<512, 256, 0, stream>>>(
        w_ih_l0, w_hh_l0, b_ih_l0, b_hh_l0,
        w_ih_l1, w_hh_l1, b_ih_l1, b_hh_l1,
        in_proj_w, x_proj_w, out_proj_w, wsu, wsf);

    dim3 grid(BB / NBR, 2);

    // layer 0: x fp32 (DIN=128) -> l0out bf16; zero init states; finals -> H1/C1
    layer_mfma<128, float, short><<<grid, BLK, 0, stream>>>(
        x, wsu + U_L0,
        wsu + U_WC0, wsu + U_INP, wsu + U_XP, wsu + U_OUTP,
        wsf + F_BSUM0, conv_w, conv_b, dt_proj_w, dt_proj_b, D_m,
        wsf + F_H0, wsf + F_C0, wsf + F_H1, wsf + F_C1);

    // layer 1: l0out bf16 (DIN=512) -> d_out fp32; init from H1/C1
    layer_mfma<512, short, float><<<grid, BLK, 0, stream>>>(
        wsu + U_L0, (float*)d_out,
        wsu + U_WC1, wsu + U_INP, wsu + U_XP, wsu + U_OUTP,
        wsf + F_BSUM1, conv_w, conv_b, dt_proj_w, dt_proj_b, D_m,
        wsf + F_H1, wsf + F_C1, wsf + F_H0, wsf + F_C0);
}